// Round 1
// baseline (104.170 us; speedup 1.0000x reference)
//
#include <hip/hip_runtime.h>

// Problem constants (match reference):
// B=64, N=10000, D=128, F=4
#define PB 64
#define PN 10000
#define PD 128
#define PF 4

// ---------------------------------------------------------------------------
// Kernel 1: partial mean-sum over N slices.
// grid = (B, S), block = 256.
// Thread t: d4 = t & 31 (float4 column within the 128-float row),
//           r0 = t >> 5 (row phase 0..7). Coalesced float4 row reads.
// Each block writes 128 floats of partial sum for its (b, slice).
// ---------------------------------------------------------------------------
__global__ __launch_bounds__(256) void partial_sum_kernel(
    const float* __restrict__ H, float* __restrict__ partial,
    int S, int rows_per_slice) {
  const int b = blockIdx.x;
  const int s = blockIdx.y;
  const int t = threadIdx.x;
  const int d4 = t & 31;
  const int r0 = t >> 5;

  const int n_begin = s * rows_per_slice;
  int n_end = n_begin + rows_per_slice;
  if (n_end > PN) n_end = PN;

  const float4* __restrict__ Hrow =
      reinterpret_cast<const float4*>(H + (size_t)b * PN * PD);

  float4 acc = make_float4(0.f, 0.f, 0.f, 0.f);
  for (int n = n_begin + r0; n < n_end; n += 8) {
    float4 v = Hrow[(size_t)n * (PD / 4) + d4];
    acc.x += v.x; acc.y += v.y; acc.z += v.z; acc.w += v.w;
  }

  __shared__ float4 smem[256];
  smem[t] = acc;
  __syncthreads();

  if (t < 32) {
    float4 sum = smem[t];
#pragma unroll
    for (int j = 1; j < 8; ++j) {
      float4 v = smem[t + 32 * j];
      sum.x += v.x; sum.y += v.y; sum.z += v.z; sum.w += v.w;
    }
    reinterpret_cast<float4*>(partial + ((size_t)b * S + s) * PD)[t] = sum;
  }
}

// ---------------------------------------------------------------------------
// Kernel 2: finalize. grid = B, block = 128 (thread = output column d).
//  - reduce S partials -> mean
//  - gather 4 indexed rows, ReLU-clamp
//  - emb (640 floats) in LDS, matvec vs W (640x128), ReLU, store
// ---------------------------------------------------------------------------
__global__ __launch_bounds__(128) void finalize_kernel(
    const float* __restrict__ H, const int* __restrict__ indice,
    const float* __restrict__ W, const float* __restrict__ partial,
    float* __restrict__ out, int S) {
  const int b = blockIdx.x;
  const int d = threadIdx.x;  // 0..127

  __shared__ float emb[(PF + 1) * PD];  // 640 floats

  // mean over N
  float sum = 0.f;
  for (int s = 0; s < S; ++s) {
    sum += partial[((size_t)b * S + s) * PD + d];
  }
  emb[PF * PD + d] = sum * (1.0f / (float)PN);

  // gathered rows, ReLU-clamped (equals one-hot*H reduce_max since N>1)
#pragma unroll
  for (int f = 0; f < PF; ++f) {
    const int idx = indice[b * PF + f];
    const float v = H[((size_t)b * PN + (size_t)idx) * PD + d];
    emb[f * PD + d] = fmaxf(v, 0.f);
  }
  __syncthreads();

  // out[b, d] = relu( sum_k emb[k] * W[k, d] )
  float acc = 0.f;
#pragma unroll 4
  for (int k = 0; k < (PF + 1) * PD; ++k) {
    acc = fmaf(emb[k], W[(size_t)k * PD + d], acc);
  }
  out[(size_t)b * PD + d] = fmaxf(acc, 0.f);
}

extern "C" void kernel_launch(void* const* d_in, const int* in_sizes, int n_in,
                              void* d_out, int out_size, void* d_ws, size_t ws_size,
                              hipStream_t stream) {
  const float* H = (const float*)d_in[0];
  const int* indice = (const int*)d_in[1];
  const float* W = (const float*)d_in[2];
  float* out = (float*)d_out;
  float* partial = (float*)d_ws;

  // Slices: want ~2048 blocks for occupancy; cap by workspace.
  int S = 32;
  const size_t per_slice_bytes = (size_t)PB * PD * sizeof(float);
  while (S > 1 && (size_t)S * per_slice_bytes > ws_size) S >>= 1;
  const int rows_per_slice = (PN + S - 1) / S;

  dim3 grid1(PB, S);
  partial_sum_kernel<<<grid1, 256, 0, stream>>>(H, partial, S, rows_per_slice);
  finalize_kernel<<<PB, 128, 0, stream>>>(H, indice, W, partial, out, S);
}

// Round 3
// 57.681 us; speedup vs baseline: 1.8060x; 1.8060x over previous
//
#include <hip/hip_runtime.h>

// Problem constants (match reference): B=64, N=10000, D=128, F=4
#define PB 64
#define PN 10000
#define PD 128
#define PF 4
#define S_SLICES 32  // partial-sum slices over N; ws needs 32*64*128*4 = 1 MB

typedef float f4v __attribute__((ext_vector_type(4)));

// ---------------------------------------------------------------------------
// Kernel 1: partial mean-sum over N slices.
// grid = (B, S), block = 256. Thread t: d4 = t&31 (float4 column), r0 = t>>5
// (row phase 0..7). 4-way unrolled with independent accumulators so 4
// nontemporal 16B loads are in flight per wave.
// ---------------------------------------------------------------------------
__global__ __launch_bounds__(256) void partial_sum_kernel(
    const float* __restrict__ H, float* __restrict__ partial,
    int rows_per_slice) {
  const int b = blockIdx.x;
  const int s = blockIdx.y;
  const int t = threadIdx.x;
  const int d4 = t & 31;
  const int r0 = t >> 5;

  const int n_begin = s * rows_per_slice;
  int n_end = n_begin + rows_per_slice;
  if (n_end > PN) n_end = PN;

  const f4v* __restrict__ Hb =
      reinterpret_cast<const f4v*>(H) + (size_t)b * PN * (PD / 4);

  f4v a0 = (f4v)(0.f), a1 = (f4v)(0.f), a2 = (f4v)(0.f), a3 = (f4v)(0.f);

  int n = n_begin + r0;
  for (; n + 24 < n_end; n += 32) {
    f4v v0 = __builtin_nontemporal_load(Hb + (size_t)n * 32 + d4);
    f4v v1 = __builtin_nontemporal_load(Hb + (size_t)(n + 8) * 32 + d4);
    f4v v2 = __builtin_nontemporal_load(Hb + (size_t)(n + 16) * 32 + d4);
    f4v v3 = __builtin_nontemporal_load(Hb + (size_t)(n + 24) * 32 + d4);
    a0 += v0; a1 += v1; a2 += v2; a3 += v3;
  }
  for (; n < n_end; n += 8) {
    a0 += __builtin_nontemporal_load(Hb + (size_t)n * 32 + d4);
  }
  a0 = (a0 + a1) + (a2 + a3);

  __shared__ f4v smem[256];
  smem[t] = a0;
  __syncthreads();

  if (t < 32) {
    f4v sum = smem[t];
#pragma unroll
    for (int j = 1; j < 8; ++j) sum += smem[t + 32 * j];
    reinterpret_cast<f4v*>(partial)[((size_t)b * S_SLICES + s) * 32 + t] = sum;
  }
}

// ---------------------------------------------------------------------------
// Kernel 2: finalize. grid = B, block = 512.
//  - reduce S partials -> mean; gather 4 rows + ReLU; emb (640 f) in LDS
//  - matvec: 16 k-slices x 40 k, float4 W loads, LDS tree-reduce, ReLU, store
// ---------------------------------------------------------------------------
__global__ __launch_bounds__(512) void finalize_kernel(
    const float* __restrict__ H, const int* __restrict__ indice,
    const float* __restrict__ W, const float* __restrict__ partial,
    float* __restrict__ out) {
  const int b = blockIdx.x;
  const int t = threadIdx.x;

  __shared__ float emb[(PF + 1) * PD];  // 640 floats
  __shared__ f4v red[16][32];           // 8 KB

  // Gathered rows, ReLU-clamped: f = t>>7 (0..3), d = t&127
  {
    const int f = t >> 7;
    const int d = t & 127;
    const int idx = indice[b * PF + f];
    emb[f * PD + d] = fmaxf(H[((size_t)b * PN + (size_t)idx) * PD + d], 0.f);
  }
  // Mean row: first 128 threads reduce the S partials
  if (t < PD) {
    const float* p = partial + (size_t)b * S_SLICES * PD + t;
    float sum = 0.f;
#pragma unroll
    for (int s = 0; s < S_SLICES; ++s) sum += p[(size_t)s * PD];
    emb[PF * PD + t] = sum * (1.0f / (float)PN);
  }
  __syncthreads();

  // Matvec: thread (w, d4) accumulates k in [w*40, w*40+40) for 4 columns
  const int d4 = t & 31;
  const int w = t >> 5;  // 0..15
  const f4v* __restrict__ W4 = reinterpret_cast<const f4v*>(W);
  f4v acc = (f4v)(0.f);
  const int k0 = w * 40;
#pragma unroll
  for (int kk = 0; kk < 40; ++kk) {
    const int k = k0 + kk;
    const float e = emb[k];
    const f4v wv = W4[(size_t)k * 32 + d4];
    acc += e * wv;
  }
  red[w][d4] = acc;
  __syncthreads();
  if (w < 8) red[w][d4] += red[w + 8][d4];
  __syncthreads();
  if (w < 4) red[w][d4] += red[w + 4][d4];
  __syncthreads();
  if (w < 2) red[w][d4] += red[w + 2][d4];
  __syncthreads();
  if (w == 0) {
    f4v r = red[0][d4] + red[1][d4];
    f4v o;
    o.x = fmaxf(r.x, 0.f); o.y = fmaxf(r.y, 0.f);
    o.z = fmaxf(r.z, 0.f); o.w = fmaxf(r.w, 0.f);
    reinterpret_cast<f4v*>(out)[(size_t)b * 32 + d4] = o;
  }
}

extern "C" void kernel_launch(void* const* d_in, const int* in_sizes, int n_in,
                              void* d_out, int out_size, void* d_ws, size_t ws_size,
                              hipStream_t stream) {
  const float* H = (const float*)d_in[0];
  const int* indice = (const int*)d_in[1];
  const float* W = (const float*)d_in[2];
  float* out = (float*)d_out;
  float* partial = (float*)d_ws;

  const int rows_per_slice = (PN + S_SLICES - 1) / S_SLICES;

  dim3 grid1(PB, S_SLICES);
  partial_sum_kernel<<<grid1, 256, 0, stream>>>(H, partial, rows_per_slice);
  finalize_kernel<<<PB, 512, 0, stream>>>(H, indice, W, partial, out);
}